// Round 1
// baseline (324.301 us; speedup 1.0000x reference)
//
#include <hip/hip_runtime.h>
#include <hip/hip_bf16.h>

#ifndef M_PI
#define M_PI 3.14159265358979323846
#endif

static constexpr int B_ = 128;   // batch
static constexpr int N_ = 3136;  // tokens (56*56)
static constexpr int C_ = 96;    // channels
// weight_c: [N][49][2] -> 98 floats per token

// One block per token n: computes y[b, n, :] = circular_conv(x[b, n, :], h_n)
// for all 128 batches, where h_n = irfft(w_n, n=96) (backward norm,
// imag parts of DC/Nyquist ignored, matching pocketfft c2r).
__global__ __launch_bounds__(192) void gfilter_conv_kernel(
    const float* __restrict__ x, const float* __restrict__ wc,
    float* __restrict__ y) {
  const int n = blockIdx.x;
  const int tid = threadIdx.x;

  // LDS: swizzled transposed x tile + replicated filter + scratch for h build
  __shared__ float At[96 * 132];  // row t (96 rows), pitch 132 floats (33 f4)
  __shared__ float hrep[192];     // h duplicated twice
  __shared__ float wsh[98];
  __shared__ float cs[96];
  __shared__ float sn[96];

  // ---- phase 1: load weights, twiddles, and stage x (transposed) ----
  if (tid < 98) wsh[tid] = wc[n * 98 + tid];
  if (tid < 96) {
    float s, c;
    sincosf((float)(2.0 * M_PI / 96.0) * (float)tid, &s, &c);
    cs[tid] = c;
    sn[tid] = s;
  }

  // stage: 128 rows x 24 float4 = 3072 float4, 16 per thread.
  // lane -> (b = fidx/24, t4 = fidx%24): consecutive lanes read consecutive
  // 16B within a row segment (coalesced). Write transposed with XOR swizzle
  // in float4 units: col_group = (b>>2) ^ (t4&7).
  for (int p = 0; p < 16; ++p) {
    const int fidx = p * 192 + tid;  // 0..3071
    const int b = fidx / 24;
    const int t4 = fidx - b * 24;
    const float4 v = *reinterpret_cast<const float4*>(
        x + ((size_t)b * N_ + n) * C_ + 4 * t4);
    const int col = 4 * ((b >> 2) ^ (t4 & 7)) + (b & 3);
    float vv[4] = {v.x, v.y, v.z, v.w};
#pragma unroll
    for (int i = 0; i < 4; ++i) {
      At[(4 * t4 + i) * 132 + col] = vv[i];
    }
  }
  __syncthreads();

  // ---- phase 2: build h_n from weights (96 lanes) ----
  if (tid < 96) {
    const int c = tid;
    float acc = wsh[0] + ((c & 1) ? -wsh[96] : wsh[96]);  // DC + Nyquist (re only)
    int idx = c;  // (k*c) % 96, incremental
    for (int k = 1; k <= 47; ++k) {
      acc += 2.0f * (wsh[2 * k] * cs[idx] - wsh[2 * k + 1] * sn[idx]);
      idx += c;
      if (idx >= 96) idx -= 96;
    }
    const float hv = acc * (1.0f / 96.0f);
    hrep[c] = hv;
    hrep[c + 96] = hv;
  }
  __syncthreads();

  // ---- phase 3: conv main loop ----
  // thread tile: 4 batches x 16 channels. 192 threads = 32 (b-tiles) x 6 (c-tiles)
  const int tidx = tid % 6;  // c-tile
  const int tidy = tid / 6;  // b-tile 0..31
  const int c0 = tidx * 16;

  float acc[4][16];
#pragma unroll
  for (int i = 0; i < 4; ++i)
#pragma unroll
    for (int j = 0; j < 16; ++j) acc[i][j] = 0.0f;

  // sliding register window of h: window_t[j] = h[(c0 + j - t) mod 96]
  // stored circularly at w[(j - t) & 15]
  float w[16];
#pragma unroll
  for (int j = 0; j < 16; ++j) w[j] = hrep[c0 + j];

  const float4* At4 = reinterpret_cast<const float4*>(At);

#pragma unroll 1
  for (int tt = 0; tt < 96; tt += 16) {
#pragma unroll
    for (int s = 0; s < 16; ++s) {
      const int t = tt + s;
      const float4 a = At4[t * 33 + (tidy ^ ((t >> 2) & 7))];
      float av[4] = {a.x, a.y, a.z, a.w};
#pragma unroll
      for (int i = 0; i < 4; ++i)
#pragma unroll
        for (int j = 0; j < 16; ++j)
          acc[i][j] = fmaf(av[i], w[(j - s) & 15], acc[i][j]);
      // slide window: new bottom element h[(c0 - t - 1) mod 96] overwrites the
      // just-consumed top (physical reg (15 - s) & 15). Harmless dead load at t=95.
      w[(15 - s) & 15] = hrep[c0 + 95 - t];
    }
  }

  // ---- epilogue: coalesced float4 stores ----
  const int b0 = tidy * 4;
#pragma unroll
  for (int i = 0; i < 4; ++i) {
    float* yp = y + ((size_t)(b0 + i) * N_ + n) * C_ + c0;
#pragma unroll
    for (int q = 0; q < 4; ++q) {
      float4 o = make_float4(acc[i][4 * q + 0], acc[i][4 * q + 1],
                             acc[i][4 * q + 2], acc[i][4 * q + 3]);
      *reinterpret_cast<float4*>(yp + 4 * q) = o;
    }
  }
}

extern "C" void kernel_launch(void* const* d_in, const int* in_sizes, int n_in,
                              void* d_out, int out_size, void* d_ws, size_t ws_size,
                              hipStream_t stream) {
  const float* x = (const float*)d_in[0];   // [B, N, C] fp32
  const float* wc = (const float*)d_in[1];  // [N, 49, 2] fp32
  float* y = (float*)d_out;                 // [B, N, C] fp32

  hipLaunchKernelGGL(gfilter_conv_kernel, dim3(N_), dim3(192), 0, stream,
                     x, wc, y);
}

// Round 2
// 284.726 us; speedup vs baseline: 1.1390x; 1.1390x over previous
//
#include <hip/hip_runtime.h>
#include <hip/hip_bf16.h>

#ifndef M_PI
#define M_PI 3.14159265358979323846
#endif

static constexpr int B_ = 128;   // batch
static constexpr int N_ = 3136;  // tokens
static constexpr int C_ = 96;    // channels
static constexpr int PITCH = 104;  // bf16 elems per LDS row (2-way bank alias only)

typedef short short8 __attribute__((ext_vector_type(8)));
typedef float float4v __attribute__((ext_vector_type(4)));

static __device__ __forceinline__ unsigned short f2bf(float f) {
  __hip_bfloat16 b = __float2bfloat16(f);
  return *reinterpret_cast<unsigned short*>(&b);
}

// One block per token n. y[:,n,:] = x[:,n,:] (128x96) @ Ht_n (96x96) via bf16 MFMA,
// where Ht_n[k][c]... stored transposed: Ht[c][k] = h_n[(c-k) mod 96],
// h_n = irfft(w_n, 96) backward-norm (Im of DC/Nyquist ignored = pocketfft c2r).
__global__ __launch_bounds__(256, 3) void gf_mfma_kernel(
    const float* __restrict__ x, const float* __restrict__ wc,
    float* __restrict__ y) {
  const int n = blockIdx.x;
  const int tid = threadIdx.x;

  __shared__ __align__(16) unsigned short Asm[128 * PITCH];  // 26624 B, bf16 x
  __shared__ __align__(16) unsigned short Ht[96 * PITCH];    // 19968 B, bf16 filter matrix
  __shared__ float wsh[98];
  __shared__ float cs[96];
  __shared__ float sn[96];
  __shared__ unsigned short hrevd[192];  // hrevd[j] = bf16(h[(192 - j) % 96])

  // ---- issue x global loads early (12 float4 per thread) ----
  float4 xv[12];
  const float* xbase = x + (size_t)n * C_;
#pragma unroll
  for (int p = 0; p < 12; ++p) {
    const int fidx = p * 256 + tid;  // 0..3071
    const int b = fidx / 24;
    const int t4 = fidx - b * 24;
    xv[p] = *reinterpret_cast<const float4*>(xbase + (size_t)b * (N_ * C_) + 4 * t4);
  }

  // ---- weights + twiddle tables ----
  if (tid < 98) wsh[tid] = wc[n * 98 + tid];
  if (tid < 96) {
    float s, c;
    sincosf((float)(2.0 * M_PI / 96.0) * (float)tid, &s, &c);
    cs[tid] = c;
    sn[tid] = s;
  }
  __syncthreads();

  // ---- build h (96 lanes), write reversed-duplicated bf16 copy ----
  if (tid < 96) {
    const int c = tid;
    float acc = wsh[0] + ((c & 1) ? -wsh[96] : wsh[96]);
    int idx = c;
    for (int k = 1; k <= 47; ++k) {
      acc += 2.0f * (wsh[2 * k] * cs[idx] - wsh[2 * k + 1] * sn[idx]);
      idx += c;
      if (idx >= 96) idx -= 96;
    }
    const unsigned short hb = f2bf(acc * (1.0f / 96.0f));
    // hrevd[j] = h[(192-j)%96]  ->  lane d writes j = 96-d, and j = (d==0 ? 0 : 192-d)
    hrevd[96 - c] = hb;
    hrevd[(c == 0) ? 0 : (192 - c)] = hb;
  }

  // ---- convert staged x to bf16, write Asm (independent of h-build) ----
#pragma unroll
  for (int p = 0; p < 12; ++p) {
    const int fidx = p * 256 + tid;
    const int b = fidx / 24;
    const int t4 = fidx - b * 24;
    ushort4 o;
    o.x = f2bf(xv[p].x);
    o.y = f2bf(xv[p].y);
    o.z = f2bf(xv[p].z);
    o.w = f2bf(xv[p].w);
    *reinterpret_cast<ushort4*>(&Asm[b * PITCH + 4 * t4]) = o;
  }
  __syncthreads();

  // ---- build Ht[c][k] = hrevd[96 + k - c], pairs per thread ----
  for (int j = tid; j < 96 * 48; j += 256) {
    const int c = j / 48;
    const int kp = j - c * 48;  // k pair index, k = 2*kp
    const int m = 96 - c + 2 * kp;  // in [1, 190]
    const unsigned int lo = hrevd[m];
    const unsigned int hi = hrevd[m + 1];
    *reinterpret_cast<unsigned int*>(&Ht[c * PITCH + 2 * kp]) = lo | (hi << 16);
  }
  __syncthreads();

  // ---- MFMA main: 4 waves, wave wv owns M-tiles {2wv, 2wv+1} x all 6 N-tiles ----
  const int wv = tid >> 6;
  const int l = tid & 63;
  const int lrow = l & 15;   // M-row / N-col within tile
  const int lk = l >> 4;     // k-group

  float4v acc[2][6];
#pragma unroll
  for (int mt = 0; mt < 2; ++mt)
#pragma unroll
    for (int nt = 0; nt < 6; ++nt)
#pragma unroll
      for (int i = 0; i < 4; ++i) acc[mt][nt][i] = 0.0f;

  short8 afr[2][3];
#pragma unroll
  for (int mt = 0; mt < 2; ++mt)
#pragma unroll
    for (int kq = 0; kq < 3; ++kq)
      afr[mt][kq] = *reinterpret_cast<const short8*>(
          &Asm[((wv * 2 + mt) * 16 + lrow) * PITCH + kq * 32 + lk * 8]);

#pragma unroll
  for (int nt = 0; nt < 6; ++nt) {
#pragma unroll
    for (int kq = 0; kq < 3; ++kq) {
      const short8 bfr = *reinterpret_cast<const short8*>(
          &Ht[(nt * 16 + lrow) * PITCH + kq * 32 + lk * 8]);
      acc[0][nt] = __builtin_amdgcn_mfma_f32_16x16x32_bf16(afr[0][kq], bfr, acc[0][nt], 0, 0, 0);
      acc[1][nt] = __builtin_amdgcn_mfma_f32_16x16x32_bf16(afr[1][kq], bfr, acc[1][nt], 0, 0, 0);
    }
  }

  // ---- epilogue: C/D layout col = lane&15, row = (lane>>4)*4 + reg ----
#pragma unroll
  for (int mt = 0; mt < 2; ++mt) {
    const int brow0 = (wv * 2 + mt) * 16 + lk * 4;
#pragma unroll
    for (int i = 0; i < 4; ++i) {
      float* yp = y + (size_t)(brow0 + i) * (N_ * C_) + (size_t)n * C_;
#pragma unroll
      for (int nt = 0; nt < 6; ++nt) {
        yp[nt * 16 + lrow] = acc[mt][nt][i];
      }
    }
  }
}

extern "C" void kernel_launch(void* const* d_in, const int* in_sizes, int n_in,
                              void* d_out, int out_size, void* d_ws, size_t ws_size,
                              hipStream_t stream) {
  const float* x = (const float*)d_in[0];   // [B, N, C] fp32
  const float* wc = (const float*)d_in[1];  // [N, 49, 2] fp32
  float* y = (float*)d_out;                 // [B, N, C] fp32

  hipLaunchKernelGGL(gf_mfma_kernel, dim3(N_), dim3(256), 0, stream, x, wc, y);
}